// Round 1
// baseline (2670.733 us; speedup 1.0000x reference)
//
#include <hip/hip_runtime.h>

// Problem constants (from reference)
#define N_ITEMS   100000
#define EMBED_DIM 64
#define N_REL     3
#define N_EDGES   3200000
#define TOTAL_EDGES ((long long)N_REL * N_EDGES)

// Kernel 1: accumulate per-relation degree sums.
// One thread per (relation, edge). deg layout: [N_REL][N_ITEMS].
__global__ void deg_kernel(const int* __restrict__ rows,
                           const float* __restrict__ vals,
                           float* __restrict__ deg) {
    long long i = (long long)blockIdx.x * blockDim.x + threadIdx.x;
    if (i >= TOTAL_EDGES) return;
    int r = (int)(i / N_EDGES);
    int row = rows[i];
    atomicAdd(&deg[(long long)r * N_ITEMS + row], vals[i]);
}

// Kernel 2: deg -> 1 / (3 * max(deg, 1))  (folds the /n_rel)
__global__ void inv_kernel(float* __restrict__ deg) {
    int i = blockIdx.x * blockDim.x + threadIdx.x;
    if (i >= N_REL * N_ITEMS) return;
    float d = deg[i];
    d = fmaxf(d, 1.0f);
    deg[i] = 1.0f / (3.0f * d);
}

// Kernel 3: scatter messages. Wave-per-edge, lane-per-dim.
// out was pre-initialized with item_embeddings (residual), so atomics add on top.
__global__ void scatter_kernel(const float* __restrict__ E,
                               const int* __restrict__ rows,
                               const int* __restrict__ cols,
                               const float* __restrict__ vals,
                               const float* __restrict__ inv,
                               float* __restrict__ out) {
    long long t = (long long)blockIdx.x * blockDim.x + threadIdx.x;
    long long edge = t >> 6;           // wave-uniform
    int d = (int)(t & 63);             // lane = embedding dim
    if (edge >= TOTAL_EDGES) return;
    int r = (int)(edge / N_EDGES);
    int row = rows[edge];
    int col = cols[edge];
    float w = vals[edge] * inv[r * N_ITEMS + row];
    float msg = w * E[(long long)col * EMBED_DIM + d];
    atomicAdd(&out[(long long)row * EMBED_DIM + d], msg);
}

extern "C" void kernel_launch(void* const* d_in, const int* in_sizes, int n_in,
                              void* d_out, int out_size, void* d_ws, size_t ws_size,
                              hipStream_t stream) {
    const float* E    = (const float*)d_in[0];  // [N_ITEMS, 64] fp32
    const int*   rows = (const int*)d_in[1];    // [3, E] int
    const int*   cols = (const int*)d_in[2];    // [3, E] int
    const float* vals = (const float*)d_in[3];  // [3, E] fp32
    float* out = (float*)d_out;                 // [N_ITEMS, 64] fp32

    float* deg = (float*)d_ws;                  // [3, N_ITEMS] fp32 (1.2 MB)

    // 1) zero degree accumulators
    hipMemsetAsync(deg, 0, (size_t)N_REL * N_ITEMS * sizeof(float), stream);

    // 2) degree accumulation: one thread per (r, edge)
    {
        long long total = TOTAL_EDGES;
        int block = 256;
        long long grid = (total + block - 1) / block;
        deg_kernel<<<(unsigned)grid, block, 0, stream>>>(rows, vals, deg);
    }

    // 3) deg -> 1/(3*max(deg,1))
    {
        int total = N_REL * N_ITEMS;
        int block = 256;
        int grid = (total + block - 1) / block;
        inv_kernel<<<grid, block, 0, stream>>>(deg);
    }

    // 4) out = item_embeddings (residual term)
    hipMemcpyAsync(out, E, (size_t)N_ITEMS * EMBED_DIM * sizeof(float),
                   hipMemcpyDeviceToDevice, stream);

    // 5) scatter: wave-per-edge, lane-per-dim, atomic accumulate into out
    {
        long long threads = TOTAL_EDGES * 64;
        int block = 256;
        long long grid = (threads + block - 1) / block;
        scatter_kernel<<<(unsigned)grid, block, 0, stream>>>(E, rows, cols, vals, deg, out);
    }
}